// Round 11
// baseline (86.635 us; speedup 1.0000x reference)
//
#include <hip/hip_runtime.h>

#define B_ 8
#define N_ 512
#define D_ 256
#define H_ 8
#define HD_ 32
#define E_ 8192
#define EA_ 32

#define LOG1EM6 -13.815510557964274f
#define SCALE 0.17677669529663687f

typedef _Float16 half8 __attribute__((ext_vector_type(8)));
typedef _Float16 half4t __attribute__((ext_vector_type(4)));
typedef __fp16 fp16x2 __attribute__((ext_vector_type(2)));
typedef float f32x16 __attribute__((ext_vector_type(16)));

// ---------------------------------------------------------------------------
// Kernel 0: fast fill of selT with 0xFF (negative sentinel).
// The runtime's fillBuffer kernel ran at ~180 GB/s and cost 45us of the 86us
// total (r10 counters). 2048 blocks x 256 thr x one int4 store = coalesced.
// ---------------------------------------------------------------------------
__global__ __launch_bounds__(256) void fill_sel(int4* __restrict__ p)
{
    int i = blockIdx.x * 256 + threadIdx.x;       // 0..524287
    p[i] = make_int4(-1, -1, -1, -1);
}

// ---------------------------------------------------------------------------
// Kernel 1: QKV projection GEMM (f32 core, proven). Epilogue emits f16:
//   Qh[b][h][n][32] (pre-scaled by 1/sqrt(hd)), Kh[b][h][n][32],
//   Vth[b][h][d][n] (transposed, for MFMA B-fragments).
// ---------------------------------------------------------------------------
__global__ __launch_bounds__(256) void qkv_gemm(
    const float* __restrict__ x, const float* __restrict__ W,
    const float* __restrict__ bias,
    _Float16* __restrict__ Qh, _Float16* __restrict__ Kh,
    _Float16* __restrict__ Vth)
{
    __shared__ float As[16][64];
    __shared__ float Bs[16][64];
    const int tid = threadIdx.x;
    const int m0 = blockIdx.y * 64;
    const int n0 = blockIdx.x * 64;
    const int tx = tid & 15, ty = tid >> 4;

    float acc[4][4];
#pragma unroll
    for (int i = 0; i < 4; i++)
#pragma unroll
        for (int j = 0; j < 4; j++) acc[i][j] = 0.0f;

    for (int kc = 0; kc < 256; kc += 16) {
        {
            int r  = tid >> 2;
            int c4 = tid & 3;
            float4 v = *(const float4*)&x[(m0 + r) * 256 + kc + c4 * 4];
            As[c4 * 4 + 0][r] = v.x;
            As[c4 * 4 + 1][r] = v.y;
            As[c4 * 4 + 2][r] = v.z;
            As[c4 * 4 + 3][r] = v.w;
        }
        {
            int kr = tid >> 4;
            int c4 = tid & 15;
            *(float4*)&Bs[kr][c4 * 4] =
                *(const float4*)&W[(kc + kr) * 768 + n0 + c4 * 4];
        }
        __syncthreads();
#pragma unroll
        for (int k = 0; k < 16; k++) {
            float a[4], bb[4];
            *(float4*)&a[0]  = *(float4*)&As[k][ty * 4];
            *(float4*)&bb[0] = *(float4*)&Bs[k][tx * 4];
#pragma unroll
            for (int i = 0; i < 4; i++)
#pragma unroll
                for (int j = 0; j < 4; j++) acc[i][j] += a[i] * bb[j];
        }
        __syncthreads();
    }

    const int col0  = n0 + tx * 4;
    const int which = col0 >> 8;
    const int h     = (col0 >> 5) & 7;
    const int hd0   = col0 & 31;
    const int b     = m0 >> 9;
    const int nr0   = (m0 & 511) + ty * 4;

    if (which < 2) {
        _Float16* base = (which == 0) ? Qh : Kh;
        const float sc = (which == 0) ? SCALE : 1.0f;
#pragma unroll
        for (int i = 0; i < 4; i++) {
            half4t hv;
#pragma unroll
            for (int j = 0; j < 4; j++)
                hv[j] = (_Float16)((acc[i][j] + bias[col0 + j]) * sc);
            *(half4t*)&base[(((size_t)(b * H_ + h)) * N_ + nr0 + i) * HD_ + hd0] = hv;
        }
    } else {
        // V transposed: Vth[b][h][d][n]
#pragma unroll
        for (int j = 0; j < 4; j++) {
            half4t hv;
            float bb = bias[col0 + j];
#pragma unroll
            for (int i = 0; i < 4; i++)
                hv[i] = (_Float16)(acc[i][j] + bb);
            *(half4t*)&Vth[(((size_t)(b * H_ + h)) * HD_ + hd0 + j) * N_ + nr0] = hv;
        }
    }
}

// ---------------------------------------------------------------------------
// Kernel 2: adj transpose + f16 convert: adjTh[b][v][u] = (f16) adj[b][u][v]
// ---------------------------------------------------------------------------
__global__ __launch_bounds__(256) void adj_transpose(
    const float* __restrict__ adj, _Float16* __restrict__ adjTh)
{
    __shared__ float t[64][65];
    const int bid = blockIdx.x;           // b*64 + vt*8 + ut
    const int b = bid >> 6, vt = (bid >> 3) & 7, ut = bid & 7;
    const int u0 = ut * 64, v0 = vt * 64;
    const int r  = threadIdx.x >> 4;      // 0..15
    const int c4 = (threadIdx.x & 15) * 4;

    const float* src = adj + ((size_t)b * N_ + u0) * N_ + v0;
#pragma unroll
    for (int it = 0; it < 4; it++) {
        int rr = r + it * 16;
        float4 v = *(const float4*)&src[rr * N_ + c4];
        t[rr][c4 + 0] = v.x; t[rr][c4 + 1] = v.y;
        t[rr][c4 + 2] = v.z; t[rr][c4 + 3] = v.w;
    }
    __syncthreads();
    _Float16* dst = adjTh + ((size_t)b * N_ + v0) * N_ + u0;
#pragma unroll
    for (int it = 0; it < 4; it++) {
        int rr = r + it * 16;
        half4t hv;
#pragma unroll
        for (int k = 0; k < 4; k++) hv[k] = (_Float16)t[c4 + k][rr];
        *(half4t*)&dst[rr * N_ + c4] = hv;
    }
}

// ---------------------------------------------------------------------------
// Kernel 3: per-edge modified focus log + transposed scatter-winner.
// selT[b][ev][eu] = max edge id (numpy last-write-wins).
// ---------------------------------------------------------------------------
__global__ __launch_bounds__(256) void edge_kernel(
    const float* __restrict__ edge_attr, const int* __restrict__ edge_index,
    const float* __restrict__ adj,
    const float* __restrict__ ds_W, const float* __restrict__ ds_b,
    const float* __restrict__ dw_W, const float* __restrict__ dw_b,
    const float* __restrict__ shifts, const float* __restrict__ widths,
    float* __restrict__ mlog, int* __restrict__ selT)
{
    __shared__ float ea[256 * 33];
    __shared__ float dsW[256], dwW[256];
    const int tid = threadIdx.x;
    const int b   = blockIdx.x >> 5;
    const int e0  = (blockIdx.x & 31) * 256;

    const float* eabase = edge_attr + ((size_t)b * E_ + e0) * EA_;
#pragma unroll
    for (int it = 0; it < 32; it++) {
        int i = tid + it * 256;
        ea[(i >> 5) * 33 + (i & 31)] = eabase[i];
    }
    dsW[tid] = ds_W[tid];
    dwW[tid] = dw_W[tid];
    __syncthreads();

    const int e  = e0 + tid;
    const int eu = edge_index[(size_t)b * 2 * E_ + e];
    const int ev = edge_index[(size_t)b * 2 * E_ + E_ + e];
    const float d = adj[((size_t)b * N_ + eu) * N_ + ev];

    float ds[8], dw[8];
#pragma unroll
    for (int h = 0; h < 8; h++) { ds[h] = ds_b[h]; dw[h] = dw_b[h]; }
#pragma unroll
    for (int k = 0; k < 32; k++) {
        float a = ea[tid * 33 + k];
#pragma unroll
        for (int h = 0; h < 8; h++) {
            ds[h] += a * dsW[k * 8 + h];
            dw[h] += a * dwW[k * 8 + h];
        }
    }
#pragma unroll
    for (int h = 0; h < 8; h++) {
        float ms = shifts[h] + ds[h];
        float mw = widths[h] + dw[h];
        float t  = d - ms;
        float ml = fmaxf(-(t * t) / (2.0f * mw * mw + 1e-6f), LOG1EM6);
        mlog[((size_t)(b * H_ + h)) * E_ + e] = ml;
    }
    atomicMax(&selT[((size_t)b * N_ + ev) * N_ + eu], e);
}

// ---------------------------------------------------------------------------
// helpers for the MFMA attn kernel
// ---------------------------------------------------------------------------
__device__ __forceinline__ unsigned pkf16(float x, float y)
{
    fp16x2 v = __builtin_amdgcn_cvt_pkrtz(x, y);   // D.lo = x, D.hi = y
    union { fp16x2 h; unsigned u; } c; c.h = v; return c.u;
}

// Build PV A-fragment for one k-half from p[0..7] (lane-local, no shuffles).
__device__ __forceinline__ half8 pack_pfrag(const float* p)
{
    union { unsigned u[4]; half8 h; } r;
    r.u[0] = pkf16(p[0], p[1]);
    r.u[1] = pkf16(p[2], p[3]);
    r.u[2] = pkf16(p[4], p[5]);
    r.u[3] = pkf16(p[6], p[7]);
    return r.h;
}

// ---------------------------------------------------------------------------
// Kernel 4 v9 (verified r10): MFMA attention. One block per (b,h,128 rows);
// 4 waves x 32 Q-rows. Swapped QK^T (A=K, B=Q) -> S^T, col=lane&31=u.
// Two-4-block k-map used consistently for K/Q/P/V fragments. Online softmax
// with defer-max THR=8. absmax 0.0078 at threshold 0.025.
// ---------------------------------------------------------------------------
__global__ __launch_bounds__(256, 1) void attn_kernel(
    const _Float16* __restrict__ Qh, const _Float16* __restrict__ Kh,
    const _Float16* __restrict__ Vth, const _Float16* __restrict__ adjTh,
    const float* __restrict__ mlog, const int* __restrict__ selT,
    const float* __restrict__ shifts, const float* __restrict__ widths,
    const float* __restrict__ slw_arr, float* __restrict__ out)
{
    extern __shared__ char lds[];         // [0,32K): K frags, [32K,64K): V frags

    const int tid  = threadIdx.x;
    const int bid  = blockIdx.x;          // b*32 + h*4 + rt
    const int b    = bid >> 5;
    const int h    = (bid >> 2) & 7;
    const int rt   = bid & 3;
    const int wv   = tid >> 6;
    const int lane = tid & 63;
    const int hi   = lane >> 5;
    const int u0w  = rt * 128 + wv * 32;

    const _Float16* Kg = Kh  + (size_t)(b * H_ + h) * N_ * HD_;
    const _Float16* Vg = Vth + (size_t)(b * H_ + h) * HD_ * N_;
    const _Float16* Qg = Qh  + (size_t)(b * H_ + h) * N_ * HD_;

    // stage K as A-fragments (8B granules, two-4-block k-map)
#pragma unroll
    for (int it = 0; it < 16; it++) {
        int i8 = tid + it * 256;          // 0..4095
        int v  = i8 >> 3;
        int c8 = i8 & 7;
        uint2 val = ((const uint2*)Kg)[i8];
        int off = ((v >> 5) * 2048) + ((c8 >> 2) * 1024) +
                  (((c8 & 1) * 32 + (v & 31)) * 16) + (((c8 >> 1) & 1) * 8);
        *(uint2*)(lds + off) = val;
    }
    // stage V as B-fragments from Vth[d][n]
#pragma unroll
    for (int it = 0; it < 16; it++) {
        int i8 = tid + it * 256;          // 0..4095
        int d  = i8 >> 7;
        int c  = i8 & 127;
        uint2 val = ((const uint2*)Vg)[i8];
        int off = 32768 + ((c >> 3) * 2048) + (((c >> 2) & 1) * 1024) +
                  (((c & 1) * 32 + d) * 16) + (((c >> 1) & 1) * 8);
        *(uint2*)(lds + off) = val;
    }
    __syncthreads();

    // Q B-fragments (2 k-halves), two-4-block map, pre-scaled by SCALE
    half8 qf0, qf1;
    {
        const _Float16* qrow = Qg + (size_t)(u0w + (lane & 31)) * HD_;
        union { uint2 w[2]; half8 h; } q0, q1;
        q0.w[0] = *(const uint2*)(qrow + hi * 4);
        q0.w[1] = *(const uint2*)(qrow + 8 + hi * 4);
        q1.w[0] = *(const uint2*)(qrow + 16 + hi * 4);
        q1.w[1] = *(const uint2*)(qrow + 24 + hi * 4);
        qf0 = q0.h; qf1 = q1.h;
    }

    const float s_h   = shifts[h];
    const float w_h   = widths[h];
    const float inv2w = 1.0f / (2.0f * w_h * w_h + 1e-6f);
    const float slw   = slw_arr[h];
    const float* mlg  = mlog + (size_t)(b * H_ + h) * E_;
    const int ucol    = u0w + (lane & 31);

    f32x16 Oacc;
#pragma unroll
    for (int r = 0; r < 16; r++) Oacc[r] = 0.0f;
    float m = -1e30f, ssum = 0.0f;

    for (int vt = 0; vt < 16; vt++) {
        // QK^T tile (S^T): 2 MFMA over k-halves
        half8 ka0 = *(const half8*)(lds + (vt * 2 + 0) * 1024 + lane * 16);
        half8 ka1 = *(const half8*)(lds + (vt * 2 + 1) * 1024 + lane * 16);
        f32x16 C;
#pragma unroll
        for (int r = 0; r < 16; r++) C[r] = 0.0f;
        C = __builtin_amdgcn_mfma_f32_32x32x16_f16(ka0, qf0, C, 0, 0, 0);
        C = __builtin_amdgcn_mfma_f32_32x32x16_f16(ka1, qf1, C, 0, 0, 0);

        // adjust + tile max
        float p[16];
        float pmax = -1e30f;
        const int vbase = vt * 32 + 4 * hi;
#pragma unroll
        for (int r = 0; r < 16; r++) {
            int vg = vbase + (r & 3) + 8 * (r >> 2);
            int sidx = (b * N_ + vg) * N_ + ucol;
            int sv   = selT[sidx];
            float av = (float)adjTh[sidx];
            float ml = mlg[sv < 0 ? 0 : sv];
            float t  = av - s_h;
            float bl = fmaxf(-(t * t) * inv2w, LOG1EM6);
            float sc = C[r] + (sv >= 0 ? ml : bl);
            if (vg == ucol) sc += slw;
            p[r] = sc;
            pmax = fmaxf(pmax, sc);
        }
        pmax = fmaxf(pmax, __shfl_xor(pmax, 32, 64));

        // defer-max online update (T13, THR=8)
        if (!__all(pmax - m <= 8.0f)) {
            float mnew = fmaxf(m, pmax);
            float scl  = __expf(m - mnew);
#pragma unroll
            for (int r = 0; r < 16; r++) {
                int ur = (r & 3) + 8 * (r >> 2) + 4 * hi;
                Oacc[r] *= __shfl(scl, ur, 64);
            }
            ssum *= scl;
            m = mnew;
        }

        // P = exp(s - m), accumulate denominator
#pragma unroll
        for (int r = 0; r < 16; r++) {
            p[r] = __expf(p[r] - m);
            ssum += p[r];
        }

        // pack P (lane-local) + PV MFMA
        half8 pa0 = pack_pfrag(&p[0]);
        half8 pa1 = pack_pfrag(&p[8]);
        half8 vb0 = *(const half8*)(lds + 32768 + (vt * 2 + 0) * 1024 + lane * 16);
        half8 vb1 = *(const half8*)(lds + 32768 + (vt * 2 + 1) * 1024 + lane * 16);
        Oacc = __builtin_amdgcn_mfma_f32_32x32x16_f16(pa0, vb0, Oacc, 0, 0, 0);
        Oacc = __builtin_amdgcn_mfma_f32_32x32x16_f16(pa1, vb1, Oacc, 0, 0, 0);
    }

    // finalize
    float stot = ssum + __shfl_xor(ssum, 32, 64);
    float rs = 1.0f / stot;
#pragma unroll
    for (int r = 0; r < 16; r++) {
        int ur = (r & 3) + 8 * (r >> 2) + 4 * hi;
        float o = Oacc[r] * __shfl(rs, ur, 64);
        int ug = u0w + ur;
        out[((size_t)(b * N_ + ug)) * D_ + h * HD_ + (lane & 31)] = o;
    }
}

// ---------------------------------------------------------------------------
extern "C" void kernel_launch(void* const* d_in, const int* in_sizes, int n_in,
                              void* d_out, int out_size, void* d_ws, size_t ws_size,
                              hipStream_t stream)
{
    const float* x          = (const float*)d_in[0];
    const float* adj        = (const float*)d_in[1];
    const int*   edge_index = (const int*)d_in[2];
    const float* edge_attr  = (const float*)d_in[3];
    const float* qkv_W      = (const float*)d_in[6];
    const float* qkv_b      = (const float*)d_in[7];
    const float* ds_W       = (const float*)d_in[12];
    const float* ds_b       = (const float*)d_in[13];
    const float* dw_W       = (const float*)d_in[14];
    const float* dw_b       = (const float*)d_in[15];
    const float* shifts     = (const float*)d_in[16];
    const float* widths     = (const float*)d_in[17];
    const float* slw        = (const float*)d_in[18];
    float* out = (float*)d_out;

    // workspace layout (20MB total)
    _Float16* Qh   = (_Float16*)d_ws;                      // 2MB
    _Float16* Kh   = Qh + (size_t)B_ * H_ * N_ * HD_;      // 2MB
    _Float16* Vth  = Kh + (size_t)B_ * H_ * N_ * HD_;      // 2MB
    float*    mlog = (float*)(Vth + (size_t)B_ * H_ * N_ * HD_);   // 2MB
    int*      selT = (int*)(mlog + (size_t)B_ * H_ * E_);  // 8MB
    _Float16* adjTh = (_Float16*)(selT + (size_t)B_ * N_ * N_);    // 4MB

    // custom fill: B*N*N ints = 524288 int4s (r10: runtime fill cost 45us)
    fill_sel<<<dim3(2048), 256, 0, stream>>>((int4*)selT);

    qkv_gemm<<<dim3(12, 64), 256, 0, stream>>>(x, qkv_W, qkv_b, Qh, Kh, Vth);

    adj_transpose<<<dim3(512), 256, 0, stream>>>(adj, adjTh);

    edge_kernel<<<dim3(256), 256, 0, stream>>>(edge_attr, edge_index, adj,
                                               ds_W, ds_b, dw_W, dw_b,
                                               shifts, widths, mlog, selT);

    hipFuncSetAttribute((const void*)attn_kernel,
                        hipFuncAttributeMaxDynamicSharedMemorySize, 65536);
    attn_kernel<<<dim3(256), 256, 65536, stream>>>(Qh, Kh, Vth, adjTh,
                                                   mlog, selT,
                                                   shifts, widths, slw, out);
}

// Round 12
// 81.436 us; speedup vs baseline: 1.0638x; 1.0638x over previous
//
#include <hip/hip_runtime.h>

#define B_ 8
#define N_ 512
#define D_ 256
#define H_ 8
#define HD_ 32
#define E_ 8192
#define EA_ 32

#define LOG1EM6 -13.815510557964274f
#define SCALE 0.17677669529663687f

typedef _Float16 half8 __attribute__((ext_vector_type(8)));
typedef _Float16 half4t __attribute__((ext_vector_type(4)));
typedef __fp16 fp16x2 __attribute__((ext_vector_type(2)));
typedef float f32x16 __attribute__((ext_vector_type(16)));

// ---------------------------------------------------------------------------
// Kernel 0: prep = selT fill (blocks 0..2047) + W transpose->f16 Wt[col][k]
// (blocks 2048..2095). r11 lesson: the 45us fills in top-5 are the HARNESS's
// 256MiB d_ws poison (WRITE_SIZE=262144KB), not our 8MB memset (~2us).
// ---------------------------------------------------------------------------
__global__ __launch_bounds__(256) void prep_kernel(
    int4* __restrict__ selT, const float* __restrict__ W,
    _Float16* __restrict__ Wt)
{
    __shared__ float t[64][65];
    const int blk = blockIdx.x;
    if (blk < 2048) {
        selT[blk * 256 + threadIdx.x] = make_int4(-1, -1, -1, -1);
        return;
    }
    const int ti = blk - 2048;            // 0..47
    const int k0 = (ti / 12) * 64;        // k-tile
    const int n0 = (ti % 12) * 64;        // n-tile
    const int r  = threadIdx.x >> 4;      // 0..15
    const int c4 = (threadIdx.x & 15) * 4;

    const float* src = W + (size_t)k0 * 768 + n0;
#pragma unroll
    for (int it = 0; it < 4; it++) {
        int rr = r + it * 16;             // k-local
        float4 v = *(const float4*)&src[rr * 768 + c4];
        t[rr][c4 + 0] = v.x; t[rr][c4 + 1] = v.y;
        t[rr][c4 + 2] = v.z; t[rr][c4 + 3] = v.w;
    }
    __syncthreads();
    _Float16* dst = Wt + (size_t)n0 * 256 + k0;
#pragma unroll
    for (int it = 0; it < 4; it++) {
        int rr = r + it * 16;             // n-local (col)
        half4t hv;
#pragma unroll
        for (int kk = 0; kk < 4; kk++) hv[kk] = (_Float16)t[c4 + kk][rr];
        *(half4t*)&dst[rr * 256 + c4] = hv;
    }
}

// ---------------------------------------------------------------------------
// Kernel 1 (v2, MFMA): QKV projection. C[4096 rows=(b,n)][768 cols] = x@Wt^T.
// 64x64 tile, 4 waves, each wave one 32x32 C-tile, K=256 -> 16 MFMA/wave.
// Fragment conventions identical to the verified attn kernel:
//   two-4-block k-map (k = ks*16 + hb*8 + lhi*4 + j), frags prearranged in
//   LDS, read as linear lane*16; C/D col=lane&31, row=(r&3)+8*(r>>2)+4*hi.
// Staging granule map (row-in-lane) gives conflict-free LDS writes; the
// strided global sources are L2-absorbed (x=4MB, Wt=0.4MB).
// Epilogue: bias + f16 convert, Q pre-scaled, V stored transposed.
// ---------------------------------------------------------------------------
__global__ __launch_bounds__(256) void qkv_gemm(
    const float* __restrict__ x, const _Float16* __restrict__ Wt,
    const float* __restrict__ bias,
    _Float16* __restrict__ Qh, _Float16* __restrict__ Kh,
    _Float16* __restrict__ Vth)
{
    extern __shared__ char lds[];         // [0,32K) A frags, [32K,64K) B frags
    const int tid = threadIdx.x;
    const int m0 = blockIdx.y * 64;       // row block
    const int n0 = blockIdx.x * 64;       // col block

    // stage A frags from x (f32 -> f16 RTN in reg). granule g: row=g&63,
    // k4=g>>6; dest: region (rb*16+ks)*1024 + (lhi*32 + r32)*16 + hb*8.
#pragma unroll
    for (int it = 0; it < 16; it++) {
        int g   = tid + it * 256;         // 0..4095
        int row = g & 63, k4 = g >> 6;
        float4 v = *(const float4*)&x[(size_t)(m0 + row) * 256 + k4 * 4];
        union { _Float16 h[4]; uint2 u; } c;
        c.h[0] = (_Float16)v.x; c.h[1] = (_Float16)v.y;
        c.h[2] = (_Float16)v.z; c.h[3] = (_Float16)v.w;
        int ks = k4 >> 2, hb = (k4 >> 1) & 1, lhi = k4 & 1;
        int off = (((row >> 5) * 16 + ks) << 10) +
                  ((lhi * 32 + (row & 31)) << 4) + hb * 8;
        *(uint2*)(lds + off) = c.u;
    }
    // stage B frags from Wt[col][k] (f16, 8B contiguous granules)
#pragma unroll
    for (int it = 0; it < 16; it++) {
        int g   = tid + it * 256;
        int col = g & 63, k4 = g >> 6;
        uint2 v = *(const uint2*)&Wt[(size_t)(n0 + col) * 256 + k4 * 4];
        int ks = k4 >> 2, hb = (k4 >> 1) & 1, lhi = k4 & 1;
        int off = 32768 + (((col >> 5) * 16 + ks) << 10) +
                  ((lhi * 32 + (col & 31)) << 4) + hb * 8;
        *(uint2*)(lds + off) = v;
    }
    __syncthreads();

    const int wv = tid >> 6, lane = tid & 63, hi = lane >> 5;
    const int rb = wv & 1, cb = wv >> 1;

    f32x16 acc;
#pragma unroll
    for (int r = 0; r < 16; r++) acc[r] = 0.0f;
#pragma unroll
    for (int ks = 0; ks < 16; ks++) {
        half8 af = *(const half8*)(lds + (((rb * 16 + ks) << 10)) + lane * 16);
        half8 bf = *(const half8*)(lds + 32768 + (((cb * 16 + ks) << 10)) + lane * 16);
        acc = __builtin_amdgcn_mfma_f32_32x32x16_f16(af, bf, acc, 0, 0, 0);
    }

    // epilogue
    const int col0  = n0 + cb * 32 + (lane & 31);
    const int which = col0 >> 8;          // wave-uniform (32-aligned col base)
    const int h     = (col0 >> 5) & 7;    // wave-uniform
    const int hd    = lane & 31;
    const int b     = m0 >> 9;
    const int nbase = (m0 & 511) + rb * 32;
    const float bcol = bias[col0];

    if (which < 2) {
        _Float16* base = (which == 0) ? Qh : Kh;
        const float sc = (which == 0) ? SCALE : 1.0f;
#pragma unroll
        for (int r = 0; r < 16; r++) {
            int n = nbase + (r & 3) + 8 * (r >> 2) + 4 * hi;
            base[((size_t)(b * H_ + h) * N_ + n) * HD_ + hd] =
                (_Float16)((acc[r] + bcol) * sc);
        }
    } else {
        // Vth[b][h][hd][n]: each r-quad = 4 consecutive n -> 8B stores
#pragma unroll
        for (int rq = 0; rq < 4; rq++) {
            int n = nbase + 8 * rq + 4 * hi;
            half4t hv;
#pragma unroll
            for (int j = 0; j < 4; j++)
                hv[j] = (_Float16)(acc[rq * 4 + j] + bcol);
            *(half4t*)&Vth[((size_t)(b * H_ + h) * HD_ + hd) * N_ + n] = hv;
        }
    }
}

// ---------------------------------------------------------------------------
// Kernel 2: adj transpose + f16 convert: adjTh[b][v][u] = (f16) adj[b][u][v]
// ---------------------------------------------------------------------------
__global__ __launch_bounds__(256) void adj_transpose(
    const float* __restrict__ adj, _Float16* __restrict__ adjTh)
{
    __shared__ float t[64][65];
    const int bid = blockIdx.x;           // b*64 + vt*8 + ut
    const int b = bid >> 6, vt = (bid >> 3) & 7, ut = bid & 7;
    const int u0 = ut * 64, v0 = vt * 64;
    const int r  = threadIdx.x >> 4;      // 0..15
    const int c4 = (threadIdx.x & 15) * 4;

    const float* src = adj + ((size_t)b * N_ + u0) * N_ + v0;
#pragma unroll
    for (int it = 0; it < 4; it++) {
        int rr = r + it * 16;
        float4 v = *(const float4*)&src[rr * N_ + c4];
        t[rr][c4 + 0] = v.x; t[rr][c4 + 1] = v.y;
        t[rr][c4 + 2] = v.z; t[rr][c4 + 3] = v.w;
    }
    __syncthreads();
    _Float16* dst = adjTh + ((size_t)b * N_ + v0) * N_ + u0;
#pragma unroll
    for (int it = 0; it < 4; it++) {
        int rr = r + it * 16;
        half4t hv;
#pragma unroll
        for (int k = 0; k < 4; k++) hv[k] = (_Float16)t[c4 + k][rr];
        *(half4t*)&dst[rr * N_ + c4] = hv;
    }
}

// ---------------------------------------------------------------------------
// Kernel 3: per-edge modified focus log + transposed scatter-winner.
// selT[b][ev][eu] = max edge id (numpy last-write-wins).
// ---------------------------------------------------------------------------
__global__ __launch_bounds__(256) void edge_kernel(
    const float* __restrict__ edge_attr, const int* __restrict__ edge_index,
    const float* __restrict__ adj,
    const float* __restrict__ ds_W, const float* __restrict__ ds_b,
    const float* __restrict__ dw_W, const float* __restrict__ dw_b,
    const float* __restrict__ shifts, const float* __restrict__ widths,
    float* __restrict__ mlog, int* __restrict__ selT)
{
    __shared__ float ea[256 * 33];
    __shared__ float dsW[256], dwW[256];
    const int tid = threadIdx.x;
    const int b   = blockIdx.x >> 5;
    const int e0  = (blockIdx.x & 31) * 256;

    const float* eabase = edge_attr + ((size_t)b * E_ + e0) * EA_;
#pragma unroll
    for (int it = 0; it < 32; it++) {
        int i = tid + it * 256;
        ea[(i >> 5) * 33 + (i & 31)] = eabase[i];
    }
    dsW[tid] = ds_W[tid];
    dwW[tid] = dw_W[tid];
    __syncthreads();

    const int e  = e0 + tid;
    const int eu = edge_index[(size_t)b * 2 * E_ + e];
    const int ev = edge_index[(size_t)b * 2 * E_ + E_ + e];
    const float d = adj[((size_t)b * N_ + eu) * N_ + ev];

    float ds[8], dw[8];
#pragma unroll
    for (int h = 0; h < 8; h++) { ds[h] = ds_b[h]; dw[h] = dw_b[h]; }
#pragma unroll
    for (int k = 0; k < 32; k++) {
        float a = ea[tid * 33 + k];
#pragma unroll
        for (int h = 0; h < 8; h++) {
            ds[h] += a * dsW[k * 8 + h];
            dw[h] += a * dwW[k * 8 + h];
        }
    }
#pragma unroll
    for (int h = 0; h < 8; h++) {
        float ms = shifts[h] + ds[h];
        float mw = widths[h] + dw[h];
        float t  = d - ms;
        float ml = fmaxf(-(t * t) / (2.0f * mw * mw + 1e-6f), LOG1EM6);
        mlog[((size_t)(b * H_ + h)) * E_ + e] = ml;
    }
    atomicMax(&selT[((size_t)b * N_ + ev) * N_ + eu], e);
}

// ---------------------------------------------------------------------------
// helpers for the MFMA attn kernel
// ---------------------------------------------------------------------------
__device__ __forceinline__ unsigned pkf16(float x, float y)
{
    fp16x2 v = __builtin_amdgcn_cvt_pkrtz(x, y);
    union { fp16x2 h; unsigned u; } c; c.h = v; return c.u;
}

__device__ __forceinline__ half8 pack_pfrag(const float* p)
{
    union { unsigned u[4]; half8 h; } r;
    r.u[0] = pkf16(p[0], p[1]);
    r.u[1] = pkf16(p[2], p[3]);
    r.u[2] = pkf16(p[4], p[5]);
    r.u[3] = pkf16(p[6], p[7]);
    return r.h;
}

// ---------------------------------------------------------------------------
// Kernel 4 (verified r10): MFMA attention. One block per (b,h,128 rows);
// 4 waves x 32 Q-rows. Swapped QK^T (A=K, B=Q) -> S^T, col=lane&31=u.
// Two-4-block k-map used consistently. Online softmax, defer-max THR=8.
// absmax 0.0078 at threshold 0.025.
// ---------------------------------------------------------------------------
__global__ __launch_bounds__(256, 1) void attn_kernel(
    const _Float16* __restrict__ Qh, const _Float16* __restrict__ Kh,
    const _Float16* __restrict__ Vth, const _Float16* __restrict__ adjTh,
    const float* __restrict__ mlog, const int* __restrict__ selT,
    const float* __restrict__ shifts, const float* __restrict__ widths,
    const float* __restrict__ slw_arr, float* __restrict__ out)
{
    extern __shared__ char lds[];         // [0,32K): K frags, [32K,64K): V frags

    const int tid  = threadIdx.x;
    const int bid  = blockIdx.x;          // b*32 + h*4 + rt
    const int b    = bid >> 5;
    const int h    = (bid >> 2) & 7;
    const int rt   = bid & 3;
    const int wv   = tid >> 6;
    const int lane = tid & 63;
    const int hi   = lane >> 5;
    const int u0w  = rt * 128 + wv * 32;

    const _Float16* Kg = Kh  + (size_t)(b * H_ + h) * N_ * HD_;
    const _Float16* Vg = Vth + (size_t)(b * H_ + h) * HD_ * N_;
    const _Float16* Qg = Qh  + (size_t)(b * H_ + h) * N_ * HD_;

#pragma unroll
    for (int it = 0; it < 16; it++) {
        int i8 = tid + it * 256;
        int v  = i8 >> 3;
        int c8 = i8 & 7;
        uint2 val = ((const uint2*)Kg)[i8];
        int off = ((v >> 5) * 2048) + ((c8 >> 2) * 1024) +
                  (((c8 & 1) * 32 + (v & 31)) * 16) + (((c8 >> 1) & 1) * 8);
        *(uint2*)(lds + off) = val;
    }
#pragma unroll
    for (int it = 0; it < 16; it++) {
        int i8 = tid + it * 256;
        int d  = i8 >> 7;
        int c  = i8 & 127;
        uint2 val = ((const uint2*)Vg)[i8];
        int off = 32768 + ((c >> 3) * 2048) + (((c >> 2) & 1) * 1024) +
                  (((c & 1) * 32 + d) * 16) + (((c >> 1) & 1) * 8);
        *(uint2*)(lds + off) = val;
    }
    __syncthreads();

    half8 qf0, qf1;
    {
        const _Float16* qrow = Qg + (size_t)(u0w + (lane & 31)) * HD_;
        union { uint2 w[2]; half8 h; } q0, q1;
        q0.w[0] = *(const uint2*)(qrow + hi * 4);
        q0.w[1] = *(const uint2*)(qrow + 8 + hi * 4);
        q1.w[0] = *(const uint2*)(qrow + 16 + hi * 4);
        q1.w[1] = *(const uint2*)(qrow + 24 + hi * 4);
        qf0 = q0.h; qf1 = q1.h;
    }

    const float s_h   = shifts[h];
    const float w_h   = widths[h];
    const float inv2w = 1.0f / (2.0f * w_h * w_h + 1e-6f);
    const float slw   = slw_arr[h];
    const float* mlg  = mlog + (size_t)(b * H_ + h) * E_;
    const int ucol    = u0w + (lane & 31);

    f32x16 Oacc;
#pragma unroll
    for (int r = 0; r < 16; r++) Oacc[r] = 0.0f;
    float m = -1e30f, ssum = 0.0f;

    for (int vt = 0; vt < 16; vt++) {
        half8 ka0 = *(const half8*)(lds + (vt * 2 + 0) * 1024 + lane * 16);
        half8 ka1 = *(const half8*)(lds + (vt * 2 + 1) * 1024 + lane * 16);
        f32x16 C;
#pragma unroll
        for (int r = 0; r < 16; r++) C[r] = 0.0f;
        C = __builtin_amdgcn_mfma_f32_32x32x16_f16(ka0, qf0, C, 0, 0, 0);
        C = __builtin_amdgcn_mfma_f32_32x32x16_f16(ka1, qf1, C, 0, 0, 0);

        float p[16];
        float pmax = -1e30f;
        const int vbase = vt * 32 + 4 * hi;
#pragma unroll
        for (int r = 0; r < 16; r++) {
            int vg = vbase + (r & 3) + 8 * (r >> 2);
            int sidx = (b * N_ + vg) * N_ + ucol;
            int sv   = selT[sidx];
            float av = (float)adjTh[sidx];
            float ml = mlg[sv < 0 ? 0 : sv];
            float t  = av - s_h;
            float bl = fmaxf(-(t * t) * inv2w, LOG1EM6);
            float sc = C[r] + (sv >= 0 ? ml : bl);
            if (vg == ucol) sc += slw;
            p[r] = sc;
            pmax = fmaxf(pmax, sc);
        }
        pmax = fmaxf(pmax, __shfl_xor(pmax, 32, 64));

        if (!__all(pmax - m <= 8.0f)) {
            float mnew = fmaxf(m, pmax);
            float scl  = __expf(m - mnew);
#pragma unroll
            for (int r = 0; r < 16; r++) {
                int ur = (r & 3) + 8 * (r >> 2) + 4 * hi;
                Oacc[r] *= __shfl(scl, ur, 64);
            }
            ssum *= scl;
            m = mnew;
        }

#pragma unroll
        for (int r = 0; r < 16; r++) {
            p[r] = __expf(p[r] - m);
            ssum += p[r];
        }

        half8 pa0 = pack_pfrag(&p[0]);
        half8 pa1 = pack_pfrag(&p[8]);
        half8 vb0 = *(const half8*)(lds + 32768 + (vt * 2 + 0) * 1024 + lane * 16);
        half8 vb1 = *(const half8*)(lds + 32768 + (vt * 2 + 1) * 1024 + lane * 16);
        Oacc = __builtin_amdgcn_mfma_f32_32x32x16_f16(pa0, vb0, Oacc, 0, 0, 0);
        Oacc = __builtin_amdgcn_mfma_f32_32x32x16_f16(pa1, vb1, Oacc, 0, 0, 0);
    }

    float stot = ssum + __shfl_xor(ssum, 32, 64);
    float rs = 1.0f / stot;
#pragma unroll
    for (int r = 0; r < 16; r++) {
        int ur = (r & 3) + 8 * (r >> 2) + 4 * hi;
        float o = Oacc[r] * __shfl(rs, ur, 64);
        int ug = u0w + ur;
        out[((size_t)(b * N_ + ug)) * D_ + h * HD_ + (lane & 31)] = o;
    }
}

// ---------------------------------------------------------------------------
extern "C" void kernel_launch(void* const* d_in, const int* in_sizes, int n_in,
                              void* d_out, int out_size, void* d_ws, size_t ws_size,
                              hipStream_t stream)
{
    const float* x          = (const float*)d_in[0];
    const float* adj        = (const float*)d_in[1];
    const int*   edge_index = (const int*)d_in[2];
    const float* edge_attr  = (const float*)d_in[3];
    const float* qkv_W      = (const float*)d_in[6];
    const float* qkv_b      = (const float*)d_in[7];
    const float* ds_W       = (const float*)d_in[12];
    const float* ds_b       = (const float*)d_in[13];
    const float* dw_W       = (const float*)d_in[14];
    const float* dw_b       = (const float*)d_in[15];
    const float* shifts     = (const float*)d_in[16];
    const float* widths     = (const float*)d_in[17];
    const float* slw        = (const float*)d_in[18];
    float* out = (float*)d_out;

    // workspace layout (~20.4MB)
    _Float16* Qh   = (_Float16*)d_ws;                      // 2MB
    _Float16* Kh   = Qh + (size_t)B_ * H_ * N_ * HD_;      // 2MB
    _Float16* Vth  = Kh + (size_t)B_ * H_ * N_ * HD_;      // 2MB
    float*    mlog = (float*)(Vth + (size_t)B_ * H_ * N_ * HD_);   // 2MB
    int*      selT = (int*)(mlog + (size_t)B_ * H_ * E_);  // 8MB
    _Float16* adjTh = (_Float16*)(selT + (size_t)B_ * N_ * N_);    // 4MB
    _Float16* Wt   = adjTh + (size_t)B_ * N_ * N_;         // 768*256 f16 = 384KB

    prep_kernel<<<dim3(2096), 256, 0, stream>>>((int4*)selT, qkv_W, Wt);

    hipFuncSetAttribute((const void*)qkv_gemm,
                        hipFuncAttributeMaxDynamicSharedMemorySize, 65536);
    qkv_gemm<<<dim3(12, 64), 256, 65536, stream>>>(x, Wt, qkv_b, Qh, Kh, Vth);

    adj_transpose<<<dim3(512), 256, 0, stream>>>(adj, adjTh);

    edge_kernel<<<dim3(256), 256, 0, stream>>>(edge_attr, edge_index, adj,
                                               ds_W, ds_b, dw_W, dw_b,
                                               shifts, widths, mlog, selT);

    hipFuncSetAttribute((const void*)attn_kernel,
                        hipFuncAttributeMaxDynamicSharedMemorySize, 65536);
    attn_kernel<<<dim3(256), 256, 65536, stream>>>(Qh, Kh, Vth, adjTh,
                                                   mlog, selT,
                                                   shifts, widths, slw, out);
}

// Round 13
// 63.260 us; speedup vs baseline: 1.3695x; 1.2873x over previous
//
#include <hip/hip_runtime.h>

#define B_ 8
#define N_ 512
#define D_ 256
#define H_ 8
#define HD_ 32
#define E_ 8192
#define EA_ 32

#define LOG1EM6 -13.815510557964274f
#define SCALE 0.17677669529663687f

typedef _Float16 half8 __attribute__((ext_vector_type(8)));
typedef _Float16 half4t __attribute__((ext_vector_type(4)));
typedef __fp16 fp16x2 __attribute__((ext_vector_type(2)));
typedef float f32x16 __attribute__((ext_vector_type(16)));

// ---------------------------------------------------------------------------
// Kernel 1: prep = selT fill (blocks 0..2047) + Wt transpose (2048..2095)
//           + adjTh transpose (2096..2607). All independent of each other.
// ---------------------------------------------------------------------------
__global__ __launch_bounds__(256) void prep_kernel(
    int4* __restrict__ selT, const float* __restrict__ W,
    _Float16* __restrict__ Wt,
    const float* __restrict__ adj, _Float16* __restrict__ adjTh)
{
    __shared__ float t[64][65];
    const int blk = blockIdx.x;
    if (blk < 2048) {
        selT[blk * 256 + threadIdx.x] = make_int4(-1, -1, -1, -1);
        return;
    }
    const int r  = threadIdx.x >> 4;      // 0..15
    const int c4 = (threadIdx.x & 15) * 4;

    if (blk < 2096) {
        // W (256x768) -> Wt[col][k] f16
        const int ti = blk - 2048;        // 0..47
        const int k0 = (ti / 12) * 64;
        const int n0 = (ti % 12) * 64;
        const float* src = W + (size_t)k0 * 768 + n0;
#pragma unroll
        for (int it = 0; it < 4; it++) {
            int rr = r + it * 16;
            float4 v = *(const float4*)&src[rr * 768 + c4];
            t[rr][c4 + 0] = v.x; t[rr][c4 + 1] = v.y;
            t[rr][c4 + 2] = v.z; t[rr][c4 + 3] = v.w;
        }
        __syncthreads();
        _Float16* dst = Wt + (size_t)n0 * 256 + k0;
#pragma unroll
        for (int it = 0; it < 4; it++) {
            int rr = r + it * 16;
            half4t hv;
#pragma unroll
            for (int kk = 0; kk < 4; kk++) hv[kk] = (_Float16)t[c4 + kk][rr];
            *(half4t*)&dst[rr * 256 + c4] = hv;
        }
    } else {
        // adj transpose -> f16
        const int ti = blk - 2096;        // 0..511 = b*64 + vt*8 + ut
        const int b = ti >> 6, vt = (ti >> 3) & 7, ut = ti & 7;
        const int u0 = ut * 64, v0 = vt * 64;
        const float* src = adj + ((size_t)b * N_ + u0) * N_ + v0;
#pragma unroll
        for (int it = 0; it < 4; it++) {
            int rr = r + it * 16;
            float4 v = *(const float4*)&src[rr * N_ + c4];
            t[rr][c4 + 0] = v.x; t[rr][c4 + 1] = v.y;
            t[rr][c4 + 2] = v.z; t[rr][c4 + 3] = v.w;
        }
        __syncthreads();
        _Float16* dst = adjTh + ((size_t)b * N_ + v0) * N_ + u0;
#pragma unroll
        for (int it = 0; it < 4; it++) {
            int rr = r + it * 16;
            half4t hv;
#pragma unroll
            for (int k = 0; k < 4; k++) hv[k] = (_Float16)t[c4 + k][rr];
            *(half4t*)&dst[rr * N_ + c4] = hv;
        }
    }
}

// ---------------------------------------------------------------------------
// Kernel 2: mid = qkv MFMA GEMM (blocks 0..767) + edge kernel (768..1023).
//
// qkv emits MFMA-READY FRAGMENTS directly (fragment identity chain):
//  - Q/K col-blocks: swapped mfma(Wfrag, xfrag) -> C^T, lane owns n-row,
//    acc[0..7]/acc[8..15] ARE the kh0/kh1 B-fragments attn needs.
//  - V col-blocks: normal mfma(xfrag, Wfrag), lane owns hd-col,
//    acc halves are the kh0/kh1 V B-fragments.
// Frag panels: [b][h][tile(16)][kh(2)][lane(64)][16B] = 32KB per (b,h).
// ---------------------------------------------------------------------------
__global__ __launch_bounds__(256) void mid_kernel(
    const float* __restrict__ x, const _Float16* __restrict__ Wt,
    const float* __restrict__ bias,
    _Float16* __restrict__ Qf, _Float16* __restrict__ Kf,
    _Float16* __restrict__ Vf,
    const float* __restrict__ edge_attr, const int* __restrict__ edge_index,
    const float* __restrict__ adj,
    const float* __restrict__ ds_W, const float* __restrict__ ds_b,
    const float* __restrict__ dw_W, const float* __restrict__ dw_b,
    const float* __restrict__ shifts, const float* __restrict__ widths,
    float* __restrict__ mlog, int* __restrict__ selT)
{
    extern __shared__ char lds[];
    const int tid = threadIdx.x;
    const int blk = blockIdx.x;

    if (blk < 768) {
        // ---------------- qkv GEMM ----------------
        const int m0 = (blk / 12) * 64;
        const int n0 = (blk % 12) * 64;

        // stage A frags from x (f32 -> f16 RTN)
#pragma unroll
        for (int it = 0; it < 16; it++) {
            int g   = tid + it * 256;
            int row = g & 63, k4 = g >> 6;
            float4 v = *(const float4*)&x[(size_t)(m0 + row) * 256 + k4 * 4];
            union { _Float16 h[4]; uint2 u; } c;
            c.h[0] = (_Float16)v.x; c.h[1] = (_Float16)v.y;
            c.h[2] = (_Float16)v.z; c.h[3] = (_Float16)v.w;
            int ks = k4 >> 2, hb = (k4 >> 1) & 1, lhi = k4 & 1;
            int off = (((row >> 5) * 16 + ks) << 10) +
                      ((lhi * 32 + (row & 31)) << 4) + hb * 8;
            *(uint2*)(lds + off) = c.u;
        }
        // stage B frags from Wt[col][k]
#pragma unroll
        for (int it = 0; it < 16; it++) {
            int g   = tid + it * 256;
            int col = g & 63, k4 = g >> 6;
            uint2 v = *(const uint2*)&Wt[(size_t)(n0 + col) * 256 + k4 * 4];
            int ks = k4 >> 2, hb = (k4 >> 1) & 1, lhi = k4 & 1;
            int off = 32768 + (((col >> 5) * 16 + ks) << 10) +
                      ((lhi * 32 + (col & 31)) << 4) + hb * 8;
            *(uint2*)(lds + off) = v;
        }
        __syncthreads();

        const int wv = tid >> 6, lane = tid & 63, hi = lane >> 5;
        const int rb = wv & 1, cb = wv >> 1;
        const int c_base = n0 + cb * 32;
        const int which  = c_base >> 8;       // wave-uniform
        const int h      = (c_base >> 5) & 7; // wave-uniform
        const int b      = m0 >> 9;
        const int ut     = ((m0 & 511) >> 5) + rb;

        f32x16 acc;
#pragma unroll
        for (int r = 0; r < 16; r++) acc[r] = 0.0f;

        if (which < 2) {
            // swapped: C^T, lane owns n-row
#pragma unroll
            for (int ks = 0; ks < 16; ks++) {
                half8 af = *(const half8*)(lds + 32768 + (((cb * 16 + ks) << 10)) + lane * 16);
                half8 bf = *(const half8*)(lds + (((rb * 16 + ks) << 10)) + lane * 16);
                acc = __builtin_amdgcn_mfma_f32_32x32x16_f16(af, bf, acc, 0, 0, 0);
            }
            _Float16* dst = (which == 0) ? Qf : Kf;
            const float sc = (which == 0) ? SCALE : 1.0f;
            size_t pb = (((size_t)(b * H_ + h) * 16 + ut) * 2) * 1024;
#pragma unroll
            for (int kh = 0; kh < 2; kh++) {
                union { _Float16 h[8]; int4 q; } fr;
#pragma unroll
                for (int j = 0; j < 8; j++) {
                    int r = kh * 8 + j;
                    int hd = (r & 3) + 8 * (r >> 2) + 4 * hi;
                    fr.h[j] = (_Float16)((acc[r] + bias[c_base + hd]) * sc);
                }
                *(int4*)((char*)dst + pb + kh * 1024 + lane * 16) = fr.q;
            }
        } else {
            // normal: lane owns hd-col
#pragma unroll
            for (int ks = 0; ks < 16; ks++) {
                half8 af = *(const half8*)(lds + (((rb * 16 + ks) << 10)) + lane * 16);
                half8 bf = *(const half8*)(lds + 32768 + (((cb * 16 + ks) << 10)) + lane * 16);
                acc = __builtin_amdgcn_mfma_f32_32x32x16_f16(af, bf, acc, 0, 0, 0);
            }
            const float bcol = bias[c_base + (lane & 31)];
            size_t pb = (((size_t)(b * H_ + h) * 16 + ut) * 2) * 1024;
#pragma unroll
            for (int kh = 0; kh < 2; kh++) {
                union { _Float16 h[8]; int4 q; } fr;
#pragma unroll
                for (int j = 0; j < 8; j++)
                    fr.h[j] = (_Float16)(acc[kh * 8 + j] + bcol);
                *(int4*)((char*)Vf + pb + kh * 1024 + lane * 16) = fr.q;
            }
        }
        return;
    }

    // ---------------- edge kernel ----------------
    float* ea  = (float*)lds;                 // 256*33 floats
    float* dsW = ea + 256 * 33;
    float* dwW = dsW + 256;
    const int eb = blk - 768;
    const int b  = eb >> 5;
    const int e0 = (eb & 31) * 256;

    const float* eabase = edge_attr + ((size_t)b * E_ + e0) * EA_;
#pragma unroll
    for (int it = 0; it < 32; it++) {
        int i = tid + it * 256;
        ea[(i >> 5) * 33 + (i & 31)] = eabase[i];
    }
    dsW[tid] = ds_W[tid];
    dwW[tid] = dw_W[tid];
    __syncthreads();

    const int e  = e0 + tid;
    const int eu = edge_index[(size_t)b * 2 * E_ + e];
    const int ev = edge_index[(size_t)b * 2 * E_ + E_ + e];
    const float d = adj[((size_t)b * N_ + eu) * N_ + ev];

    float ds[8], dw[8];
#pragma unroll
    for (int h = 0; h < 8; h++) { ds[h] = ds_b[h]; dw[h] = dw_b[h]; }
#pragma unroll
    for (int k = 0; k < 32; k++) {
        float a = ea[tid * 33 + k];
#pragma unroll
        for (int h = 0; h < 8; h++) {
            ds[h] += a * dsW[k * 8 + h];
            dw[h] += a * dwW[k * 8 + h];
        }
    }
#pragma unroll
    for (int h = 0; h < 8; h++) {
        float ms = shifts[h] + ds[h];
        float mw = widths[h] + dw[h];
        float t  = d - ms;
        float ml = fmaxf(-(t * t) / (2.0f * mw * mw + 1e-6f), LOG1EM6);
        mlog[((size_t)(b * H_ + h)) * E_ + e] = ml;
    }
    atomicMax(&selT[((size_t)b * N_ + ev) * N_ + eu], e);
}

// ---------------------------------------------------------------------------
// helpers for the MFMA attn kernel
// ---------------------------------------------------------------------------
__device__ __forceinline__ unsigned pkf16(float x, float y)
{
    fp16x2 v = __builtin_amdgcn_cvt_pkrtz(x, y);
    union { fp16x2 h; unsigned u; } c; c.h = v; return c.u;
}

__device__ __forceinline__ half8 pack_pfrag(const float* p)
{
    union { unsigned u[4]; half8 h; } r;
    r.u[0] = pkf16(p[0], p[1]);
    r.u[1] = pkf16(p[2], p[3]);
    r.u[2] = pkf16(p[4], p[5]);
    r.u[3] = pkf16(p[6], p[7]);
    return r.h;
}

// ---------------------------------------------------------------------------
// Kernel 3: MFMA attention, LDS-FREE. 64-thread blocks (one wave), grid
// 1024 = B*H*16 u-tiles. K/V/Q fragments read directly from global (L2-hot
// 32KB panels, 16B/lane coalesced). Logic identical to the r10-verified
// kernel: swapped QK^T -> S^T col=lane&31=u; online softmax defer-max THR=8.
// ---------------------------------------------------------------------------
__global__ __launch_bounds__(64) void attn_kernel(
    const _Float16* __restrict__ Qf, const _Float16* __restrict__ Kf,
    const _Float16* __restrict__ Vf, const _Float16* __restrict__ adjTh,
    const float* __restrict__ mlog, const int* __restrict__ selT,
    const float* __restrict__ shifts, const float* __restrict__ widths,
    const float* __restrict__ slw_arr, float* __restrict__ out)
{
    const int bid  = blockIdx.x;          // b*128 + h*16 + ut
    const int b    = bid >> 7;
    const int h    = (bid >> 4) & 7;
    const int ut   = bid & 15;
    const int lane = threadIdx.x;
    const int hi   = lane >> 5;
    const int u0w  = ut * 32;

    const size_t panel = ((size_t)(b * H_ + h) * 16) * 2048; // bytes
    const char* Kp = (const char*)Kf + panel;
    const char* Vp = (const char*)Vf + panel;
    const char* Qp = (const char*)Qf + panel;

    half8 qf0 = *(const half8*)(Qp + (ut * 2 + 0) * 1024 + lane * 16);
    half8 qf1 = *(const half8*)(Qp + (ut * 2 + 1) * 1024 + lane * 16);

    const float s_h   = shifts[h];
    const float w_h   = widths[h];
    const float inv2w = 1.0f / (2.0f * w_h * w_h + 1e-6f);
    const float slw   = slw_arr[h];
    const float* mlg  = mlog + (size_t)(b * H_ + h) * E_;
    const int ucol    = u0w + (lane & 31);

    f32x16 Oacc;
#pragma unroll
    for (int r = 0; r < 16; r++) Oacc[r] = 0.0f;
    float m = -1e30f, ssum = 0.0f;

    for (int vt = 0; vt < 16; vt++) {
        half8 ka0 = *(const half8*)(Kp + (vt * 2 + 0) * 1024 + lane * 16);
        half8 ka1 = *(const half8*)(Kp + (vt * 2 + 1) * 1024 + lane * 16);
        f32x16 C;
#pragma unroll
        for (int r = 0; r < 16; r++) C[r] = 0.0f;
        C = __builtin_amdgcn_mfma_f32_32x32x16_f16(ka0, qf0, C, 0, 0, 0);
        C = __builtin_amdgcn_mfma_f32_32x32x16_f16(ka1, qf1, C, 0, 0, 0);

        float p[16];
        float pmax = -1e30f;
        const int vbase = vt * 32 + 4 * hi;
#pragma unroll
        for (int r = 0; r < 16; r++) {
            int vg = vbase + (r & 3) + 8 * (r >> 2);
            int sidx = (b * N_ + vg) * N_ + ucol;
            int sv   = selT[sidx];
            float av = (float)adjTh[sidx];
            float ml = mlg[sv < 0 ? 0 : sv];
            float t  = av - s_h;
            float bl = fmaxf(-(t * t) * inv2w, LOG1EM6);
            float sc = C[r] + (sv >= 0 ? ml : bl);
            if (vg == ucol) sc += slw;
            p[r] = sc;
            pmax = fmaxf(pmax, sc);
        }
        pmax = fmaxf(pmax, __shfl_xor(pmax, 32, 64));

        if (!__all(pmax - m <= 8.0f)) {
            float mnew = fmaxf(m, pmax);
            float scl  = __expf(m - mnew);
#pragma unroll
            for (int r = 0; r < 16; r++) {
                int ur = (r & 3) + 8 * (r >> 2) + 4 * hi;
                Oacc[r] *= __shfl(scl, ur, 64);
            }
            ssum *= scl;
            m = mnew;
        }

#pragma unroll
        for (int r = 0; r < 16; r++) {
            p[r] = __expf(p[r] - m);
            ssum += p[r];
        }

        half8 pa0 = pack_pfrag(&p[0]);
        half8 pa1 = pack_pfrag(&p[8]);
        half8 vb0 = *(const half8*)(Vp + (vt * 2 + 0) * 1024 + lane * 16);
        half8 vb1 = *(const half8*)(Vp + (vt * 2 + 1) * 1024 + lane * 16);
        Oacc = __builtin_amdgcn_mfma_f32_32x32x16_f16(pa0, vb0, Oacc, 0, 0, 0);
        Oacc = __builtin_amdgcn_mfma_f32_32x32x16_f16(pa1, vb1, Oacc, 0, 0, 0);
    }

    float stot = ssum + __shfl_xor(ssum, 32, 64);
    float rs = 1.0f / stot;
#pragma unroll
    for (int r = 0; r < 16; r++) {
        int ur = (r & 3) + 8 * (r >> 2) + 4 * hi;
        float o = Oacc[r] * __shfl(rs, ur, 64);
        int ug = u0w + ur;
        out[((size_t)(b * N_ + ug)) * D_ + h * HD_ + (lane & 31)] = o;
    }
}

// ---------------------------------------------------------------------------
extern "C" void kernel_launch(void* const* d_in, const int* in_sizes, int n_in,
                              void* d_out, int out_size, void* d_ws, size_t ws_size,
                              hipStream_t stream)
{
    const float* x          = (const float*)d_in[0];
    const float* adj        = (const float*)d_in[1];
    const int*   edge_index = (const int*)d_in[2];
    const float* edge_attr  = (const float*)d_in[3];
    const float* qkv_W      = (const float*)d_in[6];
    const float* qkv_b      = (const float*)d_in[7];
    const float* ds_W       = (const float*)d_in[12];
    const float* ds_b       = (const float*)d_in[13];
    const float* dw_W       = (const float*)d_in[14];
    const float* dw_b       = (const float*)d_in[15];
    const float* shifts     = (const float*)d_in[16];
    const float* widths     = (const float*)d_in[17];
    const float* slw        = (const float*)d_in[18];
    float* out = (float*)d_out;

    // workspace layout (~20.4MB)
    _Float16* Qf   = (_Float16*)d_ws;                      // 2MB
    _Float16* Kf   = Qf + (size_t)B_ * H_ * N_ * HD_;      // 2MB
    _Float16* Vf   = Kf + (size_t)B_ * H_ * N_ * HD_;      // 2MB
    float*    mlog = (float*)(Vf + (size_t)B_ * H_ * N_ * HD_);    // 2MB
    int*      selT = (int*)(mlog + (size_t)B_ * H_ * E_);  // 8MB
    _Float16* adjTh = (_Float16*)(selT + (size_t)B_ * N_ * N_);    // 4MB
    _Float16* Wt   = adjTh + (size_t)B_ * N_ * N_;         // 384KB

    prep_kernel<<<dim3(2608), 256, 0, stream>>>((int4*)selT, qkv_W, Wt,
                                                adj, adjTh);

    hipFuncSetAttribute((const void*)mid_kernel,
                        hipFuncAttributeMaxDynamicSharedMemorySize, 65536);
    mid_kernel<<<dim3(1024), 256, 65536, stream>>>(
        x, Wt, qkv_b, Qf, Kf, Vf,
        edge_attr, edge_index, adj,
        ds_W, ds_b, dw_W, dw_b, shifts, widths, mlog, selT);

    attn_kernel<<<dim3(1024), 64, 0, stream>>>(Qf, Kf, Vf, adjTh,
                                               mlog, selT,
                                               shifts, widths, slw, out);
}